// Round 5
// baseline (236.636 us; speedup 1.0000x reference)
//
#include <hip/hip_runtime.h>
#include <hip/hip_bf16.h>
#include <math.h>

// Single persistent kernel, 256 blocks x 256 threads (provably co-resident:
// __launch_bounds__(256,2) -> >=2 blocks/CU capacity = 512 >= 256 blocks).
// Software grid barrier: release fence + atomicAdd + acquire spin (agent scope).
//  phase1: conv1, 3 (n,co) planes per block -> y1 + per-(co,n) partial sums
//  phase2: BN1 finalize (per block) + BN1/ReLU inline + conv2 -> y2 + partials
//  phase3: blocks 0..31 run the relational head for batch element n=bid

#define N_BATCH 32
#define C_OUT 24
#define NPLANE (N_BATCH * C_OUT)   // 768 planes per stage
#define NBLK 256
#define TOT1 (NPLANE * 1024)
#define TOT2 (NPLANE * 256)

__device__ __forceinline__ void grid_barrier(unsigned* bar, unsigned target) {
  __syncthreads();
  if (threadIdx.x == 0) {
    __threadfence();                 // release: drain stores, wb L2 (agent/sc1)
    atomicAdd(bar, 1u);              // device-scope by default
    while (__hip_atomic_load(bar, __ATOMIC_RELAXED, __HIP_MEMORY_SCOPE_AGENT) < target) {
      __builtin_amdgcn_s_sleep(2);
    }
    __threadfence();                 // acquire: invalidate L1/L2 (agent/sc1)
  }
  __syncthreads();
}

__global__ __launch_bounds__(256, 2) void fused_kernel(
    const float* __restrict__ img,
    const float* __restrict__ ques,
    const float* __restrict__ c1w, const float* __restrict__ c1b,
    const float* __restrict__ g1,  const float* __restrict__ bt1,
    const float* __restrict__ c2w, const float* __restrict__ c2b,
    const float* __restrict__ g2,  const float* __restrict__ bt2,
    const float* __restrict__ w_rel, const float* __restrict__ b_rel,
    const float* __restrict__ w_fc1, const float* __restrict__ b_fc1,
    const float* __restrict__ w_fc2, const float* __restrict__ b_fc2,
    float* __restrict__ out,
    float* __restrict__ y1, float* __restrict__ p1,
    float* __restrict__ y2, float* __restrict__ p2,
    unsigned* __restrict__ bars) {
  int bid = blockIdx.x;
  int t = threadIdx.x;

  __shared__ float sh[256], sh2[256];
  __shared__ float s_a[C_OUT], s_b[C_OUT];
  __shared__ float s_s[26];
  __shared__ float s_rel[128];
  __shared__ float s_h[1024];

  // ---------------- phase 1: conv1, 3 planes per block ----------------
  #pragma unroll
  for (int r = 0; r < 3; r++) {
    int plane = bid * 3 + r;          // = n*24 + co
    int co = plane % C_OUT;
    int n  = plane / C_OUT;
    const float* wbase = c1w + co * 27;
    float bias = c1b[co];
    float s = 0.f, s2 = 0.f;
    float* yp = y1 + plane * 1024;
    #pragma unroll
    for (int k = 0; k < 4; k++) {
      int p = t + k * 256;
      int oh = p >> 5, ow = p & 31;
      float acc = bias;
      #pragma unroll
      for (int ci = 0; ci < 3; ci++) {
        const float* ip = img + (n * 3 + ci) * 4096;
        const float* wp = wbase + ci * 9;
        #pragma unroll
        for (int kh = 0; kh < 3; kh++) {
          int ih = oh * 2 - 1 + kh;
          if (ih < 0) continue;
          #pragma unroll
          for (int kw = 0; kw < 3; kw++) {
            int iw = ow * 2 - 1 + kw;
            if (iw < 0) continue;
            acc += ip[ih * 64 + iw] * wp[kh * 3 + kw];
          }
        }
      }
      yp[p] = acc;
      s += acc;
      s2 += acc * acc;
    }
    __syncthreads();
    sh[t] = s; sh2[t] = s2;
    __syncthreads();
    for (int off = 128; off > 0; off >>= 1) {
      if (t < off) { sh[t] += sh[t + off]; sh2[t] += sh2[t + off]; }
      __syncthreads();
    }
    if (t == 0) {
      p1[co * 32 + n] = sh[0];
      p1[NPLANE + co * 32 + n] = sh2[0];
    }
  }

  grid_barrier(&bars[0], NBLK);

  // ---------------- phase 2: BN1 finalize + conv2, 3 planes per block ----------------
  {
    if (t < C_OUT) {
      float s = 0.f, s2 = 0.f;
      #pragma unroll 4
      for (int j = 0; j < 32; j++) {
        s += p1[t * 32 + j];
        s2 += p1[NPLANE + t * 32 + j];
      }
      float mu = s * (1.f / 32768.f);
      float var = s2 * (1.f / 32768.f) - mu * mu;
      float a = rsqrtf(var + 1e-5f) * g1[t];
      s_a[t] = a;
      s_b[t] = bt1[t] - mu * a;
    }
    __syncthreads();

    int oh = t >> 4, ow = t & 15;
    #pragma unroll
    for (int r = 0; r < 3; r++) {
      int plane = bid * 3 + r;
      int co = plane % C_OUT;
      int n  = plane / C_OUT;
      float acc = c2b[co];
      const float* wbase = c2w + co * (C_OUT * 9);
      for (int ci = 0; ci < C_OUT; ci++) {
        const float* ip = y1 + (n * C_OUT + ci) * 1024;
        const float* wp = wbase + ci * 9;
        float a1 = s_a[ci], b1 = s_b[ci];
        #pragma unroll
        for (int kh = 0; kh < 3; kh++) {
          int ih = oh * 2 - 1 + kh;
          if (ih < 0) continue;
          #pragma unroll
          for (int kw = 0; kw < 3; kw++) {
            int iw = ow * 2 - 1 + kw;
            if (iw < 0) continue;
            float v = ip[ih * 32 + iw] * a1 + b1;
            v = v > 0.f ? v : 0.f;
            acc += v * wp[kh * 3 + kw];
          }
        }
      }
      y2[plane * 256 + t] = acc;

      __syncthreads();
      sh[t] = acc; sh2[t] = acc * acc;
      __syncthreads();
      for (int off = 128; off > 0; off >>= 1) {
        if (t < off) { sh[t] += sh[t + off]; sh2[t] += sh2[t + off]; }
        __syncthreads();
      }
      if (t == 0) {
        p2[co * 32 + n] = sh[0];
        p2[NPLANE + co * 32 + n] = sh2[0];
      }
    }
  }

  grid_barrier(&bars[1], NBLK);

  // ---------------- phase 3: relational head (blocks 0..31) ----------------
  if (bid < N_BATCH) {
    int nb = bid;
    if (t < C_OUT) {
      float s = 0.f, s2 = 0.f;
      #pragma unroll 4
      for (int j = 0; j < 32; j++) {
        s += p2[t * 32 + j];
        s2 += p2[NPLANE + t * 32 + j];
      }
      float mu = s * (1.f / 8192.f);
      float var = s2 * (1.f / 8192.f) - mu * mu;
      float a = rsqrtf(var + 1e-5f) * g2[t];
      s_a[t] = a;
      s_b[t] = bt2[t] - mu * a;
    }
    __syncthreads();

    // spatial sums of relu(bn(y2)): 8 lanes per channel
    if (t < 192) {
      int ch = t >> 3, l = t & 7;
      const float* p = y2 + (nb * C_OUT + ch) * 256;
      float a2 = s_a[ch], b2 = s_b[ch];
      float a = 0.f;
      #pragma unroll
      for (int j = 0; j < 32; j++) {
        float v = p[l + 8 * j] * a2 + b2;
        a += (v > 0.f ? v : 0.f);
      }
      sh[t] = a;
    }
    __syncthreads();
    if (t < 24) {
      float a = 0.f;
      #pragma unroll
      for (int l = 0; l < 8; l++) a += sh[t * 8 + l];
      s_s[t] = a;
    }
    if (t == 24 || t == 25) {
      float cs = 0.f;
      for (int i = 0; i < 16; i++) cs += -1.f + 2.f * (float)i / 15.f;
      s_s[t] = 16.f * cs;
    }
    __syncthreads();

    // relations[m] = 256 * s@(Wi+Wj)[:,m] + 65536*(ques@Wq[:,m] + b_rel[m])
    if (t < 128) {
      float acc = 0.f;
      #pragma unroll
      for (int d = 0; d < 26; d++)
        acc += s_s[d] * (w_rel[d * 128 + t] + w_rel[(26 + d) * 128 + t]);
      float q = b_rel[t];
      const float* qv = ques + nb * 128;
      for (int k = 0; k < 128; k++) q += qv[k] * w_rel[(52 + k) * 128 + t];
      s_rel[t] = 256.f * acc + 65536.f * q;
    }
    __syncthreads();

    // fc1: 4 outputs per thread
    #pragma unroll
    for (int k = 0; k < 4; k++) {
      int c = t + k * 256;
      float acc = b_fc1[c];
      #pragma unroll 8
      for (int m = 0; m < 128; m++) acc += s_rel[m] * w_fc1[m * 1024 + c];
      s_h[c] = acc > 0.f ? acc : 0.f;
    }
    __syncthreads();

    // fc2
    float a0 = 0.f, a1 = 0.f;
    #pragma unroll
    for (int k = 0; k < 4; k++) {
      int c = t + k * 256;
      float hv = s_h[c];
      a0 += hv * w_fc2[c * 2 + 0];
      a1 += hv * w_fc2[c * 2 + 1];
    }
    #pragma unroll
    for (int off = 32; off > 0; off >>= 1) {
      a0 += __shfl_down(a0, off, 64);
      a1 += __shfl_down(a1, off, 64);
    }
    int lane = t & 63, wid = t >> 6;
    __syncthreads();
    if (lane == 0) { sh[wid] = a0; sh2[wid] = a1; }
    __syncthreads();
    if (t == 0) {
      out[nb * 2 + 0] = sh[0] + sh[1] + sh[2] + sh[3] + b_fc2[0];
      out[nb * 2 + 1] = sh2[0] + sh2[1] + sh2[2] + sh2[3] + b_fc2[1];
    }
  }
}

extern "C" void kernel_launch(void* const* d_in, const int* in_sizes, int n_in,
                              void* d_out, int out_size, void* d_ws, size_t ws_size,
                              hipStream_t stream) {
  const float* image   = (const float*)d_in[0];
  const float* ques    = (const float*)d_in[1];
  const float* conv1_w = (const float*)d_in[2];
  const float* conv1_b = (const float*)d_in[3];
  const float* bn1_g   = (const float*)d_in[4];
  const float* bn1_b   = (const float*)d_in[5];
  const float* conv2_w = (const float*)d_in[6];
  const float* conv2_b = (const float*)d_in[7];
  const float* bn2_g   = (const float*)d_in[8];
  const float* bn2_b   = (const float*)d_in[9];
  const float* w_rel   = (const float*)d_in[10];
  const float* b_rel   = (const float*)d_in[11];
  const float* w_fc1   = (const float*)d_in[12];
  const float* b_fc1   = (const float*)d_in[13];
  const float* w_fc2   = (const float*)d_in[14];
  const float* b_fc2   = (const float*)d_in[15];
  float* out = (float*)d_out;

  float* ws = (float*)d_ws;
  unsigned* bars = (unsigned*)ws;  // 4 counters (16 B)
  float* p1 = ws + 4;              // 1536
  float* p2 = p1 + 2 * NPLANE;     // 1536
  float* y1 = p2 + 2 * NPLANE;     // TOT1
  float* y2 = y1 + TOT1;           // TOT2

  hipMemsetAsync(bars, 0, 16, stream);
  fused_kernel<<<NBLK, 256, 0, stream>>>(
      image, ques, conv1_w, conv1_b, bn1_g, bn1_b, conv2_w, conv2_b,
      bn2_g, bn2_b, w_rel, b_rel, w_fc1, b_fc1, w_fc2, b_fc2,
      out, y1, p1, y2, p2, bars);
}

// Round 6
// 151.135 us; speedup vs baseline: 1.5657x; 1.5657x over previous
//
#include <hip/hip_runtime.h>
#include <math.h>

// One block per batch element (32 blocks x 1024 threads).
// y1 in LDS (bf16, 48 KB); y2 in registers (6/thread) across barrier 2.
// Only cross-block data: 96 BN-stat floats via device-scope atomics.
// Grid barrier: release fetch_add + relaxed spin + single acquire load
// (no __threadfence -> no per-block full L2 writeback/invalidate storms).

#define N_BATCH 32
#define C_OUT 24

__global__ __launch_bounds__(1024) void fused_kernel(
    const float* __restrict__ img, const float* __restrict__ ques,
    const float* __restrict__ c1w, const float* __restrict__ c1b,
    const float* __restrict__ g1,  const float* __restrict__ bt1,
    const float* __restrict__ c2w, const float* __restrict__ c2b,
    const float* __restrict__ g2,  const float* __restrict__ bt2,
    const float* __restrict__ w_rel, const float* __restrict__ b_rel,
    const float* __restrict__ w_fc1, const float* __restrict__ b_fc1,
    const float* __restrict__ w_fc2, const float* __restrict__ b_fc2,
    float* __restrict__ out,
    unsigned* __restrict__ bars, float* __restrict__ gs1,
    float* __restrict__ gs2) {
  const int n = blockIdx.x;
  const int t = threadIdx.x;
  const int lane = t & 63, wid = t >> 6;

  __shared__ unsigned short y1u[24576];   // 24 ch x 32x32, bf16 raw conv1 out
  __shared__ float s_a[C_OUT], s_b[C_OUT];
  __shared__ float s_s[26];
  __shared__ float chS[C_OUT * 16], chS2[C_OUT * 16];
  __shared__ float qpart[1024];
  __shared__ float s_rel[128];
  __shared__ float s_h[1024];

  // ---------------- phase 1: conv1 (all 24 co from one register window) ----
  {
    int oh = t >> 5, ow = t & 31;
    float win[27];
    #pragma unroll
    for (int ci = 0; ci < 3; ci++)
      #pragma unroll
      for (int kh = 0; kh < 3; kh++) {
        int ih = oh * 2 - 1 + kh;
        #pragma unroll
        for (int kw = 0; kw < 3; kw++) {
          int iw = ow * 2 - 1 + kw;
          win[ci * 9 + kh * 3 + kw] =
              (ih >= 0 && iw >= 0) ? img[(n * 3 + ci) * 4096 + ih * 64 + iw] : 0.f;
        }
      }
    #pragma unroll
    for (int co = 0; co < C_OUT; co++) {
      float acc = c1b[co];
      #pragma unroll
      for (int q = 0; q < 27; q++) acc += win[q] * c1w[co * 27 + q];
      unsigned bits = __float_as_uint(acc);
      unsigned r = (bits + 0x7FFFu + ((bits >> 16) & 1u)) >> 16;  // rne
      y1u[co * 1024 + t] = (unsigned short)r;
    }
  }
  __syncthreads();

  // stats over bf16 y1: 32 lanes per channel, shuffle-reduce, atomicAdd.
  if (t < 768) {
    int ch = t >> 5, l = t & 31;
    float s = 0.f, s2 = 0.f;
    #pragma unroll
    for (int i = 0; i < 32; i++) {
      float x = __uint_as_float((unsigned)y1u[ch * 1024 + l + 32 * i] << 16);
      s += x; s2 += x * x;
    }
    #pragma unroll
    for (int off = 16; off > 0; off >>= 1) {
      s += __shfl_down(s, off, 32);
      s2 += __shfl_down(s2, off, 32);
    }
    if (l == 0) { atomicAdd(&gs1[ch], s); atomicAdd(&gs1[C_OUT + ch], s2); }
  }

  // ---------------- barrier 1 ----------------
  __syncthreads();
  if (t == 0) {
    __hip_atomic_fetch_add(&bars[0], 1u, __ATOMIC_RELEASE, __HIP_MEMORY_SCOPE_AGENT);
    while (__hip_atomic_load(&bars[0], __ATOMIC_RELAXED, __HIP_MEMORY_SCOPE_AGENT) < N_BATCH)
      __builtin_amdgcn_s_sleep(1);
    (void)__hip_atomic_load(&bars[0], __ATOMIC_ACQUIRE, __HIP_MEMORY_SCOPE_AGENT);
  }
  __syncthreads();

  // BN1 finalize
  if (t < C_OUT) {
    float s  = __hip_atomic_load(&gs1[t],         __ATOMIC_RELAXED, __HIP_MEMORY_SCOPE_AGENT);
    float s2 = __hip_atomic_load(&gs1[C_OUT + t], __ATOMIC_RELAXED, __HIP_MEMORY_SCOPE_AGENT);
    float mu = s * (1.f / 32768.f);
    float var = s2 * (1.f / 32768.f) - mu * mu;
    float a = rsqrtf(var + 1e-5f) * g1[t];
    s_a[t] = a;
    s_b[t] = bt1[t] - mu * a;
  }
  __syncthreads();

  // ---------------- phase 2: conv2, 6 co per thread (same pixel) ----------
  const int p2 = t & 255;
  const int cog = t >> 8;                       // 0..3, wave-uniform
  const int cog_u = __builtin_amdgcn_readfirstlane(cog);
  float acc2[6];
  {
    int o2h = p2 >> 4, o2w = p2 & 15;
    #pragma unroll
    for (int j = 0; j < 6; j++) acc2[j] = c2b[cog_u * 6 + j];
    for (int ci = 0; ci < C_OUT; ci++) {
      float a1 = s_a[ci], b1 = s_b[ci];
      float v[9];
      #pragma unroll
      for (int kh = 0; kh < 3; kh++) {
        int ih = o2h * 2 - 1 + kh;
        #pragma unroll
        for (int kw = 0; kw < 3; kw++) {
          int iw = o2w * 2 - 1 + kw;
          float x = 0.f;
          if (ih >= 0 && iw >= 0) {
            x = __uint_as_float((unsigned)y1u[ci * 1024 + ih * 32 + iw] << 16);
            x = x * a1 + b1;
            x = x > 0.f ? x : 0.f;
          }
          v[kh * 3 + kw] = x;
        }
      }
      #pragma unroll
      for (int j = 0; j < 6; j++) {
        const float* wp = c2w + ((cog_u * 6 + j) * C_OUT + ci) * 9;
        float a = acc2[j];
        #pragma unroll
        for (int q = 0; q < 9; q++) a += v[q] * wp[q];
        acc2[j] = a;
      }
    }
  }
  // stage-2 stats: wave-reduce per j (wave shares co), 4 slots per channel.
  #pragma unroll
  for (int j = 0; j < 6; j++) {
    float s = acc2[j], s2 = acc2[j] * acc2[j];
    #pragma unroll
    for (int off = 32; off > 0; off >>= 1) {
      s += __shfl_down(s, off, 64);
      s2 += __shfl_down(s2, off, 64);
    }
    if (lane == 0) {
      int co = cog * 6 + j;
      chS[co * 16 + (wid & 3)] = s;
      chS2[co * 16 + (wid & 3)] = s2;
    }
  }
  __syncthreads();
  if (t < C_OUT) {
    float s = 0.f, s2 = 0.f;
    #pragma unroll
    for (int j = 0; j < 4; j++) { s += chS[t * 16 + j]; s2 += chS2[t * 16 + j]; }
    atomicAdd(&gs2[t], s);
    atomicAdd(&gs2[C_OUT + t], s2);
  }

  // ---------------- barrier 2 ----------------
  __syncthreads();
  if (t == 0) {
    __hip_atomic_fetch_add(&bars[1], 1u, __ATOMIC_RELEASE, __HIP_MEMORY_SCOPE_AGENT);
    while (__hip_atomic_load(&bars[1], __ATOMIC_RELAXED, __HIP_MEMORY_SCOPE_AGENT) < N_BATCH)
      __builtin_amdgcn_s_sleep(1);
    (void)__hip_atomic_load(&bars[1], __ATOMIC_ACQUIRE, __HIP_MEMORY_SCOPE_AGENT);
  }
  __syncthreads();

  // BN2 finalize
  if (t < C_OUT) {
    float s  = __hip_atomic_load(&gs2[t],         __ATOMIC_RELAXED, __HIP_MEMORY_SCOPE_AGENT);
    float s2 = __hip_atomic_load(&gs2[C_OUT + t], __ATOMIC_RELAXED, __HIP_MEMORY_SCOPE_AGENT);
    float mu = s * (1.f / 8192.f);
    float var = s2 * (1.f / 8192.f) - mu * mu;
    float a = rsqrtf(var + 1e-5f) * g2[t];
    s_a[t] = a;
    s_b[t] = bt2[t] - mu * a;
  }
  __syncthreads();

  // ---------------- phase 3: head ----------------
  // spatial sums of relu(bn2(y2)) straight from registers
  #pragma unroll
  for (int j = 0; j < 6; j++) {
    int co = cog * 6 + j;
    float v = acc2[j] * s_a[co] + s_b[co];
    v = v > 0.f ? v : 0.f;
    #pragma unroll
    for (int off = 32; off > 0; off >>= 1) v += __shfl_down(v, off, 64);
    if (lane == 0) chS[co * 16 + (wid & 3)] = v;
  }
  __syncthreads();
  if (t < C_OUT) {
    float s = 0.f;
    #pragma unroll
    for (int j = 0; j < 4; j++) s += chS[t * 16 + j];
    s_s[t] = s;
  }
  if (t == 24 || t == 25) {
    float cs = 0.f;
    for (int i = 0; i < 16; i++) cs += -1.f + 2.f * (float)i / 15.f;
    s_s[t] = 16.f * cs;
  }
  __syncthreads();

  // relations: q-term split over 8 groups of 16
  {
    int m = t & 127, g = t >> 7;
    const float* qv = ques + n * 128;
    float q = 0.f;
    for (int k = g * 16; k < g * 16 + 16; k++)
      q += qv[k] * w_rel[(52 + k) * 128 + m];
    qpart[t] = q;
  }
  __syncthreads();
  if (t < 128) {
    float sterm = 0.f;
    #pragma unroll
    for (int d = 0; d < 26; d++)
      sterm += s_s[d] * (w_rel[d * 128 + t] + w_rel[(26 + d) * 128 + t]);
    float q = b_rel[t];
    #pragma unroll
    for (int g = 0; g < 8; g++) q += qpart[g * 128 + t];
    s_rel[t] = 256.f * sterm + 65536.f * q;
  }
  __syncthreads();

  // fc1: one output per thread
  {
    float acc = b_fc1[t];
    #pragma unroll 8
    for (int m = 0; m < 128; m++) acc += s_rel[m] * w_fc1[m * 1024 + t];
    s_h[t] = acc > 0.f ? acc : 0.f;
  }
  __syncthreads();

  // fc2
  {
    float hv = s_h[t];
    float a0 = hv * w_fc2[2 * t], a1 = hv * w_fc2[2 * t + 1];
    #pragma unroll
    for (int off = 32; off > 0; off >>= 1) {
      a0 += __shfl_down(a0, off, 64);
      a1 += __shfl_down(a1, off, 64);
    }
    if (lane == 0) { chS[wid] = a0; chS2[wid] = a1; }
  }
  __syncthreads();
  if (t == 0) {
    float a0 = 0.f, a1 = 0.f;
    #pragma unroll
    for (int i = 0; i < 16; i++) { a0 += chS[i]; a1 += chS2[i]; }
    out[n * 2 + 0] = a0 + b_fc2[0];
    out[n * 2 + 1] = a1 + b_fc2[1];
  }
}

extern "C" void kernel_launch(void* const* d_in, const int* in_sizes, int n_in,
                              void* d_out, int out_size, void* d_ws, size_t ws_size,
                              hipStream_t stream) {
  const float* image   = (const float*)d_in[0];
  const float* ques    = (const float*)d_in[1];
  const float* conv1_w = (const float*)d_in[2];
  const float* conv1_b = (const float*)d_in[3];
  const float* bn1_g   = (const float*)d_in[4];
  const float* bn1_b   = (const float*)d_in[5];
  const float* conv2_w = (const float*)d_in[6];
  const float* conv2_b = (const float*)d_in[7];
  const float* bn2_g   = (const float*)d_in[8];
  const float* bn2_b   = (const float*)d_in[9];
  const float* w_rel   = (const float*)d_in[10];
  const float* b_rel   = (const float*)d_in[11];
  const float* w_fc1   = (const float*)d_in[12];
  const float* b_fc1   = (const float*)d_in[13];
  const float* w_fc2   = (const float*)d_in[14];
  const float* b_fc2   = (const float*)d_in[15];
  float* out = (float*)d_out;

  unsigned* bars = (unsigned*)d_ws;          // 2 counters
  float* gs1 = (float*)d_ws + 2;             // 48 floats
  float* gs2 = gs1 + 48;                     // 48 floats

  hipMemsetAsync(d_ws, 0, 400, stream);
  fused_kernel<<<N_BATCH, 1024, 0, stream>>>(
      image, ques, conv1_w, conv1_b, bn1_g, bn1_b, conv2_w, conv2_b,
      bn2_g, bn2_b, w_rel, b_rel, w_fc1, b_fc1, w_fc2, b_fc2,
      out, bars, gs1, gs2);
}

// Round 7
// 145.693 us; speedup vs baseline: 1.6242x; 1.0374x over previous
//
#include <hip/hip_runtime.h>
#include <math.h>

// 192 blocks x 1024 threads: 6 blocks per batch element (n = bid&31, r = bid>>5).
// Each block: conv1 full plane into LDS (redundant across r — burns idle CUs,
// shortens serial chain), conv2 for its 4 output channels (1 output/thread),
// BN stats exchanged via device-scope atomics, fence-free spin barriers.
// No memset dispatch: block 0 zeroes counters then release-stores MAGIC flag.

#define N_BATCH 32
#define C_OUT 24
#define BPB 6
#define NBLK (N_BATCH * BPB)   // 192
#define MAGIC 0x13579BDFu

#define AGENT __HIP_MEMORY_SCOPE_AGENT

__global__ __launch_bounds__(1024) void fused_kernel(
    const float* __restrict__ img, const float* __restrict__ ques,
    const float* __restrict__ c1w, const float* __restrict__ c1b,
    const float* __restrict__ g1,  const float* __restrict__ bt1,
    const float* __restrict__ c2w, const float* __restrict__ c2b,
    const float* __restrict__ g2,  const float* __restrict__ bt2,
    const float* __restrict__ w_rel, const float* __restrict__ b_rel,
    const float* __restrict__ w_fc1, const float* __restrict__ b_fc1,
    const float* __restrict__ w_fc2, const float* __restrict__ b_fc2,
    float* __restrict__ out,
    unsigned* __restrict__ bars, float* __restrict__ gs1,
    float* __restrict__ gs2, float* __restrict__ ssum) {
  const int t = threadIdx.x;
  const int bid = blockIdx.x;
  const int lane = t & 63, wid = t >> 6;
  const int n = bid & 31;
  const int r = bid >> 5;            // 0..5 (co group)

  __shared__ unsigned short y1u[24576];   // 24ch x 32x32 bf16
  __shared__ float s_a[C_OUT], s_b[C_OUT];
  __shared__ float s_s[26];
  __shared__ float chS[16], chS2[16];
  __shared__ float qpart[1024];
  __shared__ float s_rel[128];
  __shared__ float s_h[1024];

  // ---------------- init handshake (no host memset) ----------------
  if (bid == 0) {
    if (t < 99) {
      if (t < 3)
        __hip_atomic_store(&bars[t], 0u, __ATOMIC_RELAXED, AGENT);
      else if (t < 51)
        __hip_atomic_store(&gs1[t - 3], 0.f, __ATOMIC_RELAXED, AGENT);
      else
        __hip_atomic_store(&gs2[t - 51], 0.f, __ATOMIC_RELAXED, AGENT);
    }
    __syncthreads();
    if (t == 0)
      __hip_atomic_store(&bars[3], MAGIC, __ATOMIC_RELEASE, AGENT);
  } else {
    if (t == 0) {
      while (__hip_atomic_load(&bars[3], __ATOMIC_RELAXED, AGENT) != MAGIC)
        __builtin_amdgcn_s_sleep(2);
      (void)__hip_atomic_load(&bars[3], __ATOMIC_ACQUIRE, AGENT);
    }
    __syncthreads();
  }

  // ---------------- phase 1: conv1, 1 pixel/thread, all 24 co ----------------
  {
    int oh = t >> 5, ow = t & 31;
    float win[27];
    #pragma unroll
    for (int ci = 0; ci < 3; ci++)
      #pragma unroll
      for (int kh = 0; kh < 3; kh++) {
        int ih = oh * 2 - 1 + kh;
        #pragma unroll
        for (int kw = 0; kw < 3; kw++) {
          int iw = ow * 2 - 1 + kw;
          win[ci * 9 + kh * 3 + kw] =
              (ih >= 0 && iw >= 0) ? img[(n * 3 + ci) * 4096 + ih * 64 + iw] : 0.f;
        }
      }
    #pragma unroll
    for (int co = 0; co < C_OUT; co++) {
      float acc = c1b[co];
      #pragma unroll
      for (int q = 0; q < 27; q++) acc += win[q] * c1w[co * 27 + q];
      unsigned bits = __float_as_uint(acc);
      unsigned rr = (bits + 0x7FFFu + ((bits >> 16) & 1u)) >> 16;  // rne
      y1u[co * 1024 + t] = (unsigned short)rr;
    }
  }
  __syncthreads();

  // stage-1 stats: only r==0 blocks contribute
  if (r == 0 && t < 768) {
    int ch = t >> 5, l = t & 31;
    float s = 0.f, s2 = 0.f;
    #pragma unroll
    for (int i = 0; i < 32; i++) {
      float x = __uint_as_float((unsigned)y1u[ch * 1024 + l + 32 * i] << 16);
      s += x; s2 += x * x;
    }
    #pragma unroll
    for (int off = 16; off > 0; off >>= 1) {
      s += __shfl_down(s, off, 32);
      s2 += __shfl_down(s2, off, 32);
    }
    if (l == 0) { atomicAdd(&gs1[ch], s); atomicAdd(&gs1[C_OUT + ch], s2); }
  }

  // ---------------- barrier 1 (target 32) ----------------
  __syncthreads();
  if (t == 0) {
    if (r == 0)
      __hip_atomic_fetch_add(&bars[0], 1u, __ATOMIC_RELEASE, AGENT);
    while (__hip_atomic_load(&bars[0], __ATOMIC_RELAXED, AGENT) < N_BATCH)
      __builtin_amdgcn_s_sleep(1);
    (void)__hip_atomic_load(&bars[0], __ATOMIC_ACQUIRE, AGENT);
  }
  __syncthreads();

  // BN1 finalize
  if (t < C_OUT) {
    float s  = __hip_atomic_load(&gs1[t],         __ATOMIC_RELAXED, AGENT);
    float s2 = __hip_atomic_load(&gs1[C_OUT + t], __ATOMIC_RELAXED, AGENT);
    float mu = s * (1.f / 32768.f);
    float var = s2 * (1.f / 32768.f) - mu * mu;
    float a = rsqrtf(var + 1e-5f) * g1[t];
    s_a[t] = a;
    s_b[t] = bt1[t] - mu * a;
  }
  __syncthreads();

  // ---------------- phase 2: conv2, 1 output/thread ----------------
  const int px = t & 255;
  const int slot = t >> 8;                         // 0..3, wave-uniform
  const int co2 = __builtin_amdgcn_readfirstlane(r * 4 + slot);
  float acc2;
  {
    int o2h = px >> 4, o2w = px & 15;
    acc2 = c2b[co2];
    for (int ci = 0; ci < C_OUT; ci++) {
      float a1 = s_a[ci], b1 = s_b[ci];
      const float* wp = c2w + (co2 * C_OUT + ci) * 9;
      #pragma unroll
      for (int kh = 0; kh < 3; kh++) {
        int ih = o2h * 2 - 1 + kh;
        #pragma unroll
        for (int kw = 0; kw < 3; kw++) {
          int iw = o2w * 2 - 1 + kw;
          float x = 0.f;
          if (ih >= 0 && iw >= 0) {
            x = __uint_as_float((unsigned)y1u[ci * 1024 + ih * 32 + iw] << 16);
            x = x * a1 + b1;
            x = x > 0.f ? x : 0.f;
          }
          acc2 += x * wp[kh * 3 + kw];
        }
      }
    }
  }
  // stage-2 stats: reduce over 256 px (4 waves per slot)
  {
    float s = acc2, s2 = acc2 * acc2;
    #pragma unroll
    for (int off = 32; off > 0; off >>= 1) {
      s += __shfl_down(s, off, 64);
      s2 += __shfl_down(s2, off, 64);
    }
    if (lane == 0) { chS[slot * 4 + (wid & 3)] = s; chS2[slot * 4 + (wid & 3)] = s2; }
  }
  __syncthreads();
  if (t < 4) {
    float s = 0.f, s2 = 0.f;
    #pragma unroll
    for (int j = 0; j < 4; j++) { s += chS[t * 4 + j]; s2 += chS2[t * 4 + j]; }
    atomicAdd(&gs2[r * 4 + t], s);
    atomicAdd(&gs2[C_OUT + r * 4 + t], s2);
  }

  // ---------------- barrier 2 (target 192) ----------------
  __syncthreads();
  if (t == 0) {
    __hip_atomic_fetch_add(&bars[1], 1u, __ATOMIC_RELEASE, AGENT);
    while (__hip_atomic_load(&bars[1], __ATOMIC_RELAXED, AGENT) < NBLK)
      __builtin_amdgcn_s_sleep(1);
    (void)__hip_atomic_load(&bars[1], __ATOMIC_ACQUIRE, AGENT);
  }
  __syncthreads();

  // BN2 finalize (s_a/s_b safely overwritten: last read was pre-barrier)
  if (t < C_OUT) {
    float s  = __hip_atomic_load(&gs2[t],         __ATOMIC_RELAXED, AGENT);
    float s2 = __hip_atomic_load(&gs2[C_OUT + t], __ATOMIC_RELAXED, AGENT);
    float mu = s * (1.f / 8192.f);
    float var = s2 * (1.f / 8192.f) - mu * mu;
    float a = rsqrtf(var + 1e-5f) * g2[t];
    s_a[t] = a;
    s_b[t] = bt2[t] - mu * a;
  }
  __syncthreads();

  // relu(bn2) spatial sums -> ssum[n*24+co] (single writer per slot)
  {
    float v = acc2 * s_a[co2] + s_b[co2];
    v = v > 0.f ? v : 0.f;
    #pragma unroll
    for (int off = 32; off > 0; off >>= 1) v += __shfl_down(v, off, 64);
    if (lane == 0) chS[slot * 4 + (wid & 3)] = v;
  }
  __syncthreads();
  if (t < 4) {
    float s = chS[t * 4] + chS[t * 4 + 1] + chS[t * 4 + 2] + chS[t * 4 + 3];
    __hip_atomic_store(&ssum[n * C_OUT + r * 4 + t], s, __ATOMIC_RELAXED, AGENT);
  }

  // ---------------- barrier 3 (target 192); non-head blocks exit ----------------
  __syncthreads();
  if (t == 0)
    __hip_atomic_fetch_add(&bars[2], 1u, __ATOMIC_RELEASE, AGENT);
  if (r != 0) return;
  if (t == 0) {
    while (__hip_atomic_load(&bars[2], __ATOMIC_RELAXED, AGENT) < NBLK)
      __builtin_amdgcn_s_sleep(1);
    (void)__hip_atomic_load(&bars[2], __ATOMIC_ACQUIRE, AGENT);
  }
  __syncthreads();

  // ---------------- phase 3: relational head (32 blocks) ----------------
  if (t < C_OUT)
    s_s[t] = __hip_atomic_load(&ssum[n * C_OUT + t], __ATOMIC_RELAXED, AGENT);
  if (t == 24 || t == 25) {
    float cs = 0.f;
    for (int i = 0; i < 16; i++) cs += -1.f + 2.f * (float)i / 15.f;
    s_s[t] = 16.f * cs;
  }
  // q-term partials: 8 groups of 16 k's
  {
    int m = t & 127, g = t >> 7;
    const float* qv = ques + n * 128;
    float q = 0.f;
    for (int k = g * 16; k < g * 16 + 16; k++)
      q += qv[k] * w_rel[(52 + k) * 128 + m];
    qpart[t] = q;
  }
  __syncthreads();
  if (t < 128) {
    float sterm = 0.f;
    #pragma unroll
    for (int d = 0; d < 26; d++)
      sterm += s_s[d] * (w_rel[d * 128 + t] + w_rel[(26 + d) * 128 + t]);
    float q = b_rel[t];
    #pragma unroll
    for (int g = 0; g < 8; g++) q += qpart[g * 128 + t];
    s_rel[t] = 256.f * sterm + 65536.f * q;
  }
  __syncthreads();

  // fc1
  {
    float acc = b_fc1[t];
    #pragma unroll 8
    for (int m = 0; m < 128; m++) acc += s_rel[m] * w_fc1[m * 1024 + t];
    s_h[t] = acc > 0.f ? acc : 0.f;
  }
  __syncthreads();

  // fc2
  {
    float hv = s_h[t];
    float a0 = hv * w_fc2[2 * t], a1 = hv * w_fc2[2 * t + 1];
    #pragma unroll
    for (int off = 32; off > 0; off >>= 1) {
      a0 += __shfl_down(a0, off, 64);
      a1 += __shfl_down(a1, off, 64);
    }
    if (lane == 0) { chS[wid] = a0; chS2[wid] = a1; }
  }
  __syncthreads();
  if (t == 0) {
    float a0 = 0.f, a1 = 0.f;
    #pragma unroll
    for (int i = 0; i < 16; i++) { a0 += chS[i]; a1 += chS2[i]; }
    out[n * 2 + 0] = a0 + b_fc2[0];
    out[n * 2 + 1] = a1 + b_fc2[1];
  }
}

extern "C" void kernel_launch(void* const* d_in, const int* in_sizes, int n_in,
                              void* d_out, int out_size, void* d_ws, size_t ws_size,
                              hipStream_t stream) {
  const float* image   = (const float*)d_in[0];
  const float* ques    = (const float*)d_in[1];
  const float* conv1_w = (const float*)d_in[2];
  const float* conv1_b = (const float*)d_in[3];
  const float* bn1_g   = (const float*)d_in[4];
  const float* bn1_b   = (const float*)d_in[5];
  const float* conv2_w = (const float*)d_in[6];
  const float* conv2_b = (const float*)d_in[7];
  const float* bn2_g   = (const float*)d_in[8];
  const float* bn2_b   = (const float*)d_in[9];
  const float* w_rel   = (const float*)d_in[10];
  const float* b_rel   = (const float*)d_in[11];
  const float* w_fc1   = (const float*)d_in[12];
  const float* b_fc1   = (const float*)d_in[13];
  const float* w_fc2   = (const float*)d_in[14];
  const float* b_fc2   = (const float*)d_in[15];
  float* out = (float*)d_out;

  unsigned* bars = (unsigned*)d_ws;          // 4 counters (bars[3] = init flag)
  float* gs1  = (float*)d_ws + 4;            // 48
  float* gs2  = gs1 + 48;                    // 48
  float* ssum = gs2 + 48;                    // 768

  fused_kernel<<<NBLK, 1024, 0, stream>>>(
      image, ques, conv1_w, conv1_b, bn1_g, bn1_b, conv2_w, conv2_b,
      bn2_g, bn2_b, w_rel, b_rel, w_fc1, b_fc1, w_fc2, b_fc2,
      out, bars, gs1, gs2, ssum);
}

// Round 8
// 140.246 us; speedup vs baseline: 1.6873x; 1.0388x over previous
//
#include <hip/hip_runtime.h>
#include <math.h>

// 192 blocks x 1024 threads, 6 per batch element (n = bid&31, r = bid>>5).
// NO atomic RMWs anywhere: all cross-block exchange is single-writer relaxed
// agent-scope atomic stores/loads, ordered by per-block release-stored MAGIC
// flags that waiters poll in parallel (one thread per flag).
// Barriers are scoped: BN1 = 32 flags (r==0 writers), BN2 = 32 same-r flags,
// head waits only on its 5 siblings. Non-head blocks store and exit.
// Head blocks hide w_rel/w_fc1 fetch latency between flag-post and flag-wait
// by computing the q-half of fc1 early (exact split: h = h_q + h_sterm).
// ws is 0xAA-poisoned before every call -> flags start != MAGIC, no memset.

#define N_BATCH 32
#define C_OUT 24
#define NBLK 192
#define MAGIC 0x13579BDFu
#define AGENT __HIP_MEMORY_SCOPE_AGENT
#define PITCH 33
#define CHSZ (32 * PITCH)   // 1056 ushorts per channel plane

__device__ __forceinline__ float aload(const float* p) {
  return __hip_atomic_load(p, __ATOMIC_RELAXED, AGENT);
}
__device__ __forceinline__ void astore(float* p, float v) {
  __hip_atomic_store(p, v, __ATOMIC_RELAXED, AGENT);
}
__device__ __forceinline__ void waitflag(const unsigned* f) {
  while (__hip_atomic_load(f, __ATOMIC_ACQUIRE, AGENT) != MAGIC)
    __builtin_amdgcn_s_sleep(1);
}

__global__ __launch_bounds__(1024) void fused_kernel(
    const float* __restrict__ img, const float* __restrict__ ques,
    const float* __restrict__ c1w, const float* __restrict__ c1b,
    const float* __restrict__ g1,  const float* __restrict__ bt1,
    const float* __restrict__ c2w, const float* __restrict__ c2b,
    const float* __restrict__ g2,  const float* __restrict__ bt2,
    const float* __restrict__ w_rel, const float* __restrict__ b_rel,
    const float* __restrict__ w_fc1, const float* __restrict__ b_fc1,
    const float* __restrict__ w_fc2, const float* __restrict__ b_fc2,
    float* __restrict__ out,
    unsigned* __restrict__ flags1, unsigned* __restrict__ flags2,
    unsigned* __restrict__ flags3,
    float* __restrict__ p1, float* __restrict__ p2,
    float* __restrict__ ssum) {
  const int t = threadIdx.x;
  const int bid = blockIdx.x;
  const int lane = t & 63, wid = t >> 6;
  const int n = bid & 31;
  const int r = bid >> 5;            // 0..5, owns channels r*4..r*4+3

  __shared__ unsigned short y1u[24 * CHSZ];   // ~50.7 KB, bf16, pitch-padded
  __shared__ float s_a[C_OUT], s_b[C_OUT];    // BN1 scale/shift
  __shared__ float a2[4], b2[4];              // BN2 (this block's 4 channels)
  __shared__ float chS[16], chS2[16];
  __shared__ float qpart[1024];
  __shared__ float qfull[128];
  __shared__ float s_s[26];
  __shared__ float s_rel[128];
  __shared__ float s_h[1024];

  float h_local = 0.f;   // q-half of fc1 (head blocks only)

  // ---------------- phase 1: conv1, 1 pixel/thread, all 24 co ----------------
  {
    int oh = t >> 5, ow = t & 31;
    float win[27];
    #pragma unroll
    for (int ci = 0; ci < 3; ci++)
      #pragma unroll
      for (int kh = 0; kh < 3; kh++) {
        int ih = oh * 2 - 1 + kh;
        #pragma unroll
        for (int kw = 0; kw < 3; kw++) {
          int iw = ow * 2 - 1 + kw;
          win[ci * 9 + kh * 3 + kw] =
              (ih >= 0 && iw >= 0) ? img[(n * 3 + ci) * 4096 + ih * 64 + iw] : 0.f;
        }
      }
    #pragma unroll
    for (int co = 0; co < C_OUT; co++) {
      float acc = c1b[co];
      #pragma unroll
      for (int q = 0; q < 27; q++) acc += win[q] * c1w[co * 27 + q];
      unsigned bits = __float_as_uint(acc);
      unsigned rr = (bits + 0x7FFFu + ((bits >> 16) & 1u)) >> 16;  // rne
      y1u[co * CHSZ + oh * PITCH + ow] = (unsigned short)rr;
    }
  }
  __syncthreads();

  // stage-1 stats: only r==0 blocks write p1 + flags1[n]
  if (r == 0) {
    if (t < 768) {
      int ch = t >> 5, l = t & 31;
      float s = 0.f, s2 = 0.f;
      #pragma unroll
      for (int i = 0; i < 32; i++) {
        float x = __uint_as_float((unsigned)y1u[ch * CHSZ + i * PITCH + l] << 16);
        s += x; s2 += x * x;
      }
      #pragma unroll
      for (int off = 16; off > 0; off >>= 1) {
        s += __shfl_down(s, off, 32);
        s2 += __shfl_down(s2, off, 32);
      }
      if (l == 0) {
        astore(&p1[ch * 32 + n], s);
        astore(&p1[768 + ch * 32 + n], s2);
      }
    }
    __syncthreads();
    if (t == 0)
      __hip_atomic_store(&flags1[n], MAGIC, __ATOMIC_RELEASE, AGENT);
  }

  // ---------------- wait BN1 stats + finalize (all blocks) ----------------
  if (t < 32) waitflag(&flags1[t]);
  __syncthreads();
  if (t < 768) {
    int ch = t >> 5, j = t & 31;
    float s = aload(&p1[ch * 32 + j]);
    float s2 = aload(&p1[768 + ch * 32 + j]);
    #pragma unroll
    for (int off = 16; off > 0; off >>= 1) {
      s += __shfl_down(s, off, 32);
      s2 += __shfl_down(s2, off, 32);
    }
    if (j == 0) {
      float mu = s * (1.f / 32768.f);
      float var = s2 * (1.f / 32768.f) - mu * mu;
      float a = rsqrtf(var + 1e-5f) * g1[ch];
      s_a[ch] = a;
      s_b[ch] = bt1[ch] - mu * a;
    }
  }
  __syncthreads();

  // ---------------- phase 2: conv2, 1 output/thread ----------------
  const int px = t & 255;
  const int slot = t >> 8;                         // 0..3, wave-uniform
  const int co2 = r * 4 + slot;
  float acc2;
  {
    int o2h = px >> 4, o2w = px & 15;
    acc2 = c2b[co2];
    for (int ci = 0; ci < C_OUT; ci++) {
      float a1 = s_a[ci], b1 = s_b[ci];
      const float* wp = c2w + (co2 * C_OUT + ci) * 9;
      #pragma unroll
      for (int kh = 0; kh < 3; kh++) {
        int ih = o2h * 2 - 1 + kh;
        #pragma unroll
        for (int kw = 0; kw < 3; kw++) {
          int iw = o2w * 2 - 1 + kw;
          float x = 0.f;
          if (ih >= 0 && iw >= 0) {
            x = __uint_as_float((unsigned)y1u[ci * CHSZ + ih * PITCH + iw] << 16);
            x = x * a1 + b1;
            x = x > 0.f ? x : 0.f;
          }
          acc2 += x * wp[kh * 3 + kw];
        }
      }
    }
  }
  // per-block stage-2 partials (this n, 4 channels), single-writer
  {
    float s = acc2, s2 = acc2 * acc2;
    #pragma unroll
    for (int off = 32; off > 0; off >>= 1) {
      s += __shfl_down(s, off, 64);
      s2 += __shfl_down(s2, off, 64);
    }
    if (lane == 0) { chS[slot * 4 + (wid & 3)] = s; chS2[slot * 4 + (wid & 3)] = s2; }
  }
  __syncthreads();
  if (t < 4) {
    float s = chS[t * 4] + chS[t * 4 + 1] + chS[t * 4 + 2] + chS[t * 4 + 3];
    float s2 = chS2[t * 4] + chS2[t * 4 + 1] + chS2[t * 4 + 2] + chS2[t * 4 + 3];
    astore(&p2[(r * 4 + t) * 32 + n], s);
    astore(&p2[768 + (r * 4 + t) * 32 + n], s2);
  }
  __syncthreads();
  if (t == 0)
    __hip_atomic_store(&flags2[bid], MAGIC, __ATOMIC_RELEASE, AGENT);

  // ---------------- head blocks: hide q-term + fc1 q-half here ----------------
  if (r == 0) {
    {
      int m = t & 127, g = t >> 7;
      const float* qv = ques + n * 128;
      float q = 0.f;
      for (int k = g * 16; k < g * 16 + 16; k++)
        q += qv[k] * w_rel[(52 + k) * 128 + m];
      qpart[t] = q;
    }
    __syncthreads();
    if (t < 128) {
      float q = b_rel[t];
      #pragma unroll
      for (int g = 0; g < 8; g++) q += qpart[g * 128 + t];
      qfull[t] = 65536.f * q;
    }
    __syncthreads();
    {
      float hl = b_fc1[t];
      #pragma unroll 8
      for (int m = 0; m < 128; m++) hl += qfull[m] * w_fc1[m * 1024 + t];
      h_local = hl;          // also warms L2 for the sterm pass
    }
  }

  // ---------------- wait BN2 stats for our r-group, finalize 4 channels -------
  if (t < 32) waitflag(&flags2[r * 32 + t]);
  __syncthreads();
  if (t < 128) {
    int c4 = t >> 5, j = t & 31;
    float s = aload(&p2[(r * 4 + c4) * 32 + j]);
    float s2 = aload(&p2[768 + (r * 4 + c4) * 32 + j]);
    #pragma unroll
    for (int off = 16; off > 0; off >>= 1) {
      s += __shfl_down(s, off, 32);
      s2 += __shfl_down(s2, off, 32);
    }
    if (j == 0) {
      float mu = s * (1.f / 8192.f);
      float var = s2 * (1.f / 8192.f) - mu * mu;
      float a = rsqrtf(var + 1e-5f) * g2[r * 4 + c4];
      a2[c4] = a;
      b2[c4] = bt2[r * 4 + c4] - mu * a;
    }
  }
  __syncthreads();

  // relu(bn2) spatial sums -> ssum[n*24+co], single-writer
  {
    float v = acc2 * a2[slot] + b2[slot];
    v = v > 0.f ? v : 0.f;
    #pragma unroll
    for (int off = 32; off > 0; off >>= 1) v += __shfl_down(v, off, 64);
    if (lane == 0) chS[slot * 4 + (wid & 3)] = v;
  }
  __syncthreads();
  if (t < 4)
    astore(&ssum[n * C_OUT + r * 4 + t],
           chS[t * 4] + chS[t * 4 + 1] + chS[t * 4 + 2] + chS[t * 4 + 3]);
  __syncthreads();
  if (t == 0)
    __hip_atomic_store(&flags3[bid], MAGIC, __ATOMIC_RELEASE, AGENT);

  if (r != 0) return;   // non-head blocks never wait past here

  // ---------------- phase 3: head (32 blocks), wait 5 siblings only ----------
  if (t >= 1 && t < 6) waitflag(&flags3[t * 32 + n]);
  __syncthreads();
  if (t < C_OUT) s_s[t] = aload(&ssum[n * C_OUT + t]);
  if (t == 24 || t == 25) {
    float cs = 0.f;
    for (int i = 0; i < 16; i++) cs += -1.f + 2.f * (float)i / 15.f;
    s_s[t] = 16.f * cs;
  }
  __syncthreads();
  if (t < 128) {
    float sterm = 0.f;
    #pragma unroll
    for (int d = 0; d < 26; d++)
      sterm += s_s[d] * (w_rel[d * 128 + t] + w_rel[(26 + d) * 128 + t]);
    s_rel[t] = 256.f * sterm;
  }
  __syncthreads();

  // fc1 sterm-half (w_fc1 now L2-warm) + relu
  {
    float acc = h_local;
    #pragma unroll 8
    for (int m = 0; m < 128; m++) acc += s_rel[m] * w_fc1[m * 1024 + t];
    s_h[t] = acc > 0.f ? acc : 0.f;
  }
  __syncthreads();

  // fc2
  {
    float hv = s_h[t];
    float a0 = hv * w_fc2[2 * t], a1 = hv * w_fc2[2 * t + 1];
    #pragma unroll
    for (int off = 32; off > 0; off >>= 1) {
      a0 += __shfl_down(a0, off, 64);
      a1 += __shfl_down(a1, off, 64);
    }
    if (lane == 0) { chS[wid] = a0; chS2[wid] = a1; }
  }
  __syncthreads();
  if (t == 0) {
    float a0 = 0.f, a1 = 0.f;
    #pragma unroll
    for (int i = 0; i < 16; i++) { a0 += chS[i]; a1 += chS2[i]; }
    out[n * 2 + 0] = a0 + b_fc2[0];
    out[n * 2 + 1] = a1 + b_fc2[1];
  }
}

extern "C" void kernel_launch(void* const* d_in, const int* in_sizes, int n_in,
                              void* d_out, int out_size, void* d_ws, size_t ws_size,
                              hipStream_t stream) {
  const float* image   = (const float*)d_in[0];
  const float* ques    = (const float*)d_in[1];
  const float* conv1_w = (const float*)d_in[2];
  const float* conv1_b = (const float*)d_in[3];
  const float* bn1_g   = (const float*)d_in[4];
  const float* bn1_b   = (const float*)d_in[5];
  const float* conv2_w = (const float*)d_in[6];
  const float* conv2_b = (const float*)d_in[7];
  const float* bn2_g   = (const float*)d_in[8];
  const float* bn2_b   = (const float*)d_in[9];
  const float* w_rel   = (const float*)d_in[10];
  const float* b_rel   = (const float*)d_in[11];
  const float* w_fc1   = (const float*)d_in[12];
  const float* b_fc1   = (const float*)d_in[13];
  const float* w_fc2   = (const float*)d_in[14];
  const float* b_fc2   = (const float*)d_in[15];
  float* out = (float*)d_out;

  unsigned* flags1 = (unsigned*)d_ws;          // 32
  unsigned* flags2 = flags1 + 32;              // 192
  unsigned* flags3 = flags2 + 192;             // 192  (total 416 uints)
  float* p1   = (float*)d_ws + 416;            // 1536
  float* p2   = p1 + 1536;                     // 1536
  float* ssum = p2 + 1536;                     // 768

  fused_kernel<<<NBLK, 1024, 0, stream>>>(
      image, ques, conv1_w, conv1_b, bn1_g, bn1_b, conv2_w, conv2_b,
      bn2_g, bn2_b, w_rel, b_rel, w_fc1, b_fc1, w_fc2, b_fc2,
      out, flags1, flags2, flags3, p1, p2, ssum);
}